// Round 13
// baseline (260.271 us; speedup 1.0000x reference)
//
#include <hip/hip_runtime.h>

typedef short bfx8 __attribute__((ext_vector_type(8)));
typedef float fx4 __attribute__((ext_vector_type(4)));

#define D 256
#define E_TILE 64

__device__ __forceinline__ float b2f(short s) {
  union { unsigned u; float f; } v; v.u = ((unsigned)(unsigned short)s) << 16; return v.f;
}
__device__ __forceinline__ short f2b(float f) {
  union { float f; unsigned u; } v; v.f = f;
  unsigned u = v.u;
  u += 0x7fffu + ((u >> 16) & 1u);   // RNE
  return (short)(u >> 16);
}
__device__ __forceinline__ float relu(float f) { return f > 0.f ? f : 0.f; }

// ---------------- prep: convert weights to bf16 in ws ----------------
__global__ void k_prep(const float* __restrict__ W1, const float* __restrict__ W2,
                       unsigned short* __restrict__ B1, unsigned short* __restrict__ W2b) {
  int t = blockIdx.x * 256 + threadIdx.x;
  if (t < 512 * 256) {
    int n = t >> 8, k = t & 255;
    float v = (n < 256) ? W1[n * 512 + k] : W1[(n - 256) * 512 + 256 + k];
    B1[t] = (unsigned short)f2b(v);
  } else if (t < 512 * 256 + 256 * 256) {
    int i = t - 512 * 256;
    W2b[i] = (unsigned short)f2b(W2[i]);
  }
}

// ---------------- node kernel v2 (unchanged from round 7): PQ = x @ B1^T + [b1;0] ------
__launch_bounds__(512, 1)
__global__ void k_node(const float* __restrict__ x, const unsigned short* __restrict__ B1,
                       const float* __restrict__ b1,
                       unsigned short* __restrict__ PQ, int n_nodes, int ntiles) {
  __shared__ __align__(16) short smA[64 * 264];   // 33.8 KB, stride 264 (pad 8)
  short* smT = smA;                               // [32][520] alias for store transpose
  const int tid = threadIdx.x;
  const int wave = tid >> 6, lane = tid & 63;
  const int lr = lane & 15, lg = lane >> 4;

  bfx8 bw[4][8];
  float b1v[4];
#pragma unroll
  for (int nt = 0; nt < 4; ++nt) {
    int n = wave * 64 + nt * 16 + lr;
    b1v[nt] = (n < 256) ? b1[n] : 0.f;
#pragma unroll
    for (int ks = 0; ks < 8; ++ks)
      bw[nt][ks] = *(const bfx8*)(B1 + n * 256 + ks * 32 + lg * 8);
  }

  const int r  = tid >> 3;
  const int c4 = (tid & 7) * 4;
  const int rs = tid >> 4;
  const int cs = (tid & 15) * 8;

  for (int tile = blockIdx.x; tile < ntiles; tile += gridDim.x) {
    const int m0 = tile * 64;
    {
      int m = m0 + r;
      if (m < n_nodes) {
        const float* p = x + (size_t)m * 256 + c4;
#pragma unroll
        for (int j = 0; j < 8; ++j) {
          float4 v = *(const float4*)(p + j * 32);
          short4 o = { f2b(v.x), f2b(v.y), f2b(v.z), f2b(v.w) };
          *(short4*)&smA[r * 264 + c4 + j * 32] = o;
        }
      } else {
        short4 z = {0, 0, 0, 0};
#pragma unroll
        for (int j = 0; j < 8; ++j)
          *(short4*)&smA[r * 264 + c4 + j * 32] = z;
      }
    }
    __syncthreads();

    fx4 acc[4][4] = {};
#pragma unroll
    for (int ks = 0; ks < 8; ++ks) {
      bfx8 af[4];
#pragma unroll
      for (int mt = 0; mt < 4; ++mt)
        af[mt] = *(const bfx8*)&smA[(mt * 16 + lr) * 264 + ks * 32 + lg * 8];
#pragma unroll
      for (int nt = 0; nt < 4; ++nt)
#pragma unroll
        for (int mt = 0; mt < 4; ++mt)
          acc[mt][nt] = __builtin_amdgcn_mfma_f32_16x16x32_bf16(af[mt], bw[nt][ks], acc[mt][nt], 0, 0, 0);
    }
    __syncthreads();

#pragma unroll
    for (int h = 0; h < 2; ++h) {
#pragma unroll
      for (int mt2 = 0; mt2 < 2; ++mt2) {
        const int mt = 2 * h + mt2;
#pragma unroll
        for (int nt = 0; nt < 4; ++nt)
#pragma unroll
          for (int i = 0; i < 4; ++i) {
            int mrow = mt2 * 16 + lg * 4 + i;
            int n = wave * 64 + nt * 16 + lr;
            smT[mrow * 520 + n] = f2b(acc[mt][nt][i] + b1v[nt]);
          }
      }
      __syncthreads();
      int m = m0 + h * 32 + rs;
      if (m < n_nodes) {
#pragma unroll
        for (int j = 0; j < 4; ++j) {
          int c = cs + j * 128;
          *(bfx8*)(PQ + (size_t)m * 512 + c) = *(const bfx8*)&smT[rs * 520 + c];
        }
      }
      __syncthreads();
    }
  }
}

// ---- async stage for k_edge: one global_load_lds per edge ----
// lanes 0-31 fetch P'[src[e]] (512B), lanes 32-63 fetch Q[dst[e]] (512B at +512B).
// LDS dest = raw row (wave-uniform base, lane*16 HW offsets -> contiguous 1024B).
// Wave w stages rows [16w, 16w+16) == exactly the rows wave w's fuse reads ->
// no cross-wave hazard; the two existing barriers order everything.
__device__ __forceinline__ void stage_tile(const unsigned short* __restrict__ PQ,
                                           const int* __restrict__ src,
                                           const int* __restrict__ dst,
                                           short* smRaw, int ebase, int w, int lane, int E) {
  int eidx = ebase + w * 16 + (lane & 15);
  if (eidx > E - 1) eidx = E - 1;             // clamp: tail rows load edge E-1 (finite data, rows unused)
  int vs = src[eidx];
  int vd = dst[eidx];
  const char* pqc = (const char*)PQ;
#pragma unroll
  for (int i = 0; i < 16; ++i) {
    int ss = __builtin_amdgcn_readlane(vs, i);
    int sd = __builtin_amdgcn_readlane(vd, i);
    const char* gp = (lane < 32)
        ? pqc + (size_t)ss * 1024 + (size_t)lane * 16
        : pqc + (size_t)sd * 1024 + 512 + (size_t)(lane - 32) * 16;
    __builtin_amdgcn_global_load_lds((const void*)gp, (void*)&smRaw[(w * 16 + i) * 520], 16, 0, 0);
  }
}

// ---------------- edge kernel v3: async gather -> LDS pipeline ----------------
// ROUND-8 REWRITE of the staging path only (GEMM/epilogue byte-identical to the
// proven round-7 kernel). Round-7 counters: MfmaUtil 17.4% (=15us, the MFMA
// floor), VALUBusy 27%, Occ 20% -> ~47us of the 85.5 was exposed gather latency
// (serial gather->barrier->GEMM, only 2 blocks/CU). Round-4 showed reg-prefetch
// spills (live across GEMM). global_load_lds prefetches straight to LDS with
// ZERO registers live across the GEMM; the compiler's vmcnt(0)-before-barrier
// drain lands at barrier (2), AFTER the GEMM -> full latency cover.
//   per tile: fuse(raw->smH) | (1) | stage(t+G)->raw | GEMM | epi | (2) | out
// LDS: raw 64x520 shorts (pad 8 -> 16B-aligned rows, ~min bank conflict)
//      = 66.6KB + smH 33.8KB + smS 1KB = 101.4KB -> 1 block/CU (4 waves).
// OccupancyPercent ~12.5% next profile is EXPECTED (by design), not a bug.
__launch_bounds__(256, 2)
__global__ void k_edge(const unsigned short* __restrict__ PQ,
                       const int* __restrict__ src, const int* __restrict__ dst,
                       const unsigned short* __restrict__ W2b,
                       const float* __restrict__ b2, const float* __restrict__ W3,
                       const float* __restrict__ b3, float* __restrict__ out,
                       int E, int ntiles) {
  __shared__ __align__(16) short smRaw[64 * 520];  // [edge][0:256]=P', [256:512]=Q, [512:520] pad
  __shared__ __align__(16) short smH[64 * 264];    // h1, stride 264 (pad 8)
  __shared__ float smS[4][64];
  const int tid = threadIdx.x;
  const int wave = tid >> 6, lane = tid & 63;
  const int lr = lane & 15, lg = lane >> 4;
  const int G = gridDim.x;

  // W2 fragments (this wave's 64 N rows, full K=256): 4 n-tiles x 8 k-steps
  bfx8 bw[4][8];
  float b2v[4], w3v[4];
#pragma unroll
  for (int nt = 0; nt < 4; ++nt) {
    int n = wave * 64 + nt * 16 + lr;
    b2v[nt] = b2[n];
    w3v[nt] = W3[n];
#pragma unroll
    for (int ks = 0; ks < 8; ++ks)
      bw[nt][ks] = *(const bfx8*)(W2b + n * 256 + ks * 32 + lg * 8);
  }
  const float b3v = b3[0];

  const int r = tid >> 2, cb = (tid & 3) * 8;   // fuse role: 4 thr/edge; r in [16w,16w+16) ✓
  const int t0 = blockIdx.x;

  // prologue: stage tile t0, wait for it
  if (t0 < ntiles) stage_tile(PQ, src, dst, smRaw, t0 * E_TILE, wave, lane, E);
  __syncthreads();

  for (int t = t0; t < ntiles; t += G) {
    // fuse layer1 from raw LDS: h1 = relu(P'+Q)  (b1 already folded into P')
#pragma unroll
    for (int it = 0; it < 8; ++it) {
      int c = cb + it * 32;
      bfx8 pv = *(const bfx8*)&smRaw[r * 520 + c];
      bfx8 qv = *(const bfx8*)&smRaw[r * 520 + 256 + c];
      bfx8 o;
#pragma unroll
      for (int j = 0; j < 8; ++j)
        o[j] = f2b(relu(b2f(pv[j]) + b2f(qv[j])));
      *(bfx8*)&smH[r * 264 + c] = o;
    }
    __syncthreads();                                   // (1) smH visible; no vm outstanding

    // issue next tile's gather: flies during GEMM+epilogue, drained at (2)
    if (t + G < ntiles)
      stage_tile(PQ, src, dst, smRaw, (t + G) * E_TILE, wave, lane, E);

    // layer2 GEMM: 64M x 64N per wave, K=256
    fx4 acc[4][4] = {};
#pragma unroll
    for (int ks = 0; ks < 8; ++ks) {
      bfx8 af[4];
#pragma unroll
      for (int mt = 0; mt < 4; ++mt)
        af[mt] = *(const bfx8*)&smH[(mt * 16 + lr) * 264 + ks * 32 + lg * 8];
#pragma unroll
      for (int nt = 0; nt < 4; ++nt)
#pragma unroll
        for (int mt = 0; mt < 4; ++mt)
          acc[mt][nt] = __builtin_amdgcn_mfma_f32_16x16x32_bf16(af[mt], bw[nt][ks], acc[mt][nt], 0, 0, 0);
    }

    // epilogue: relu(acc+b2) dot w3, shfl-reduce within 16-groups
#pragma unroll
    for (int mt = 0; mt < 4; ++mt)
#pragma unroll
      for (int i = 0; i < 4; ++i) {
        float p = 0.f;
#pragma unroll
        for (int nt = 0; nt < 4; ++nt)
          p += relu(acc[mt][nt][i] + b2v[nt]) * w3v[nt];
        p += __shfl_xor(p, 1);
        p += __shfl_xor(p, 2);
        p += __shfl_xor(p, 4);
        p += __shfl_xor(p, 8);
        if (lr == 0) smS[wave][mt * 16 + lg * 4 + i] = p;
      }
    __syncthreads();                                   // (2) smS visible; drains stage loads (post-GEMM)
    if (tid < 64) {
      int e = t * E_TILE + tid;
      if (e < E) out[e] = smS[0][tid] + smS[1][tid] + smS[2][tid] + smS[3][tid] + b3v;
    }
    // loop: fuse(t+G) reads raw (drained at (2)); smS(t+G) written only after next (1)
  }
}

// ---------------- fallback (if ws too small): naive fp32, 1 edge per wave ----------------
__global__ void k_fallback(const float* __restrict__ x, const int* __restrict__ src,
                           const int* __restrict__ dst, const float* __restrict__ W1,
                           const float* __restrict__ b1, const float* __restrict__ W2,
                           const float* __restrict__ b2, const float* __restrict__ W3,
                           const float* __restrict__ b3, float* __restrict__ out, int E) {
  __shared__ float smF[4][512];
  __shared__ float smG[4][256];
  int wave = threadIdx.x >> 6, lane = threadIdx.x & 63;
  int e = blockIdx.x * 4 + wave;
  bool valid = e < E;
  int ec = valid ? e : 0;
  int s = src[ec], d = dst[ec];
  for (int j = 0; j < 8; ++j) {
    int k = lane * 8 + j;
    smF[wave][k] = (k < 256) ? x[(size_t)s * 256 + k] : x[(size_t)d * 256 + k - 256];
  }
  __syncthreads();
  for (int t = 0; t < 4; ++t) {
    int n = lane + t * 64;
    float a = b1[n];
    for (int k = 0; k < 512; ++k) a += smF[wave][k] * W1[n * 512 + k];
    smG[wave][n] = relu(a);
  }
  __syncthreads();
  float p = 0.f;
  for (int t = 0; t < 4; ++t) {
    int n = lane + t * 64;
    float a = b2[n];
    for (int k = 0; k < 256; ++k) a += smG[wave][k] * W2[n * 256 + k];
    p += relu(a) * W3[n];
  }
  for (int m = 1; m < 64; m <<= 1) p += __shfl_xor(p, m);
  if (lane == 0 && valid) out[e] = p + b3[0];
}

extern "C" void kernel_launch(void* const* d_in, const int* in_sizes, int n_in,
                              void* d_out, int out_size, void* d_ws, size_t ws_size,
                              hipStream_t stream) {
  const float* x  = (const float*)d_in[0];
  const int*   src = (const int*)d_in[1];
  const int*   dst = (const int*)d_in[2];
  const float* W1 = (const float*)d_in[3];
  const float* b1 = (const float*)d_in[4];
  const float* W2 = (const float*)d_in[5];
  const float* b2 = (const float*)d_in[6];
  const float* W3 = (const float*)d_in[7];
  const float* b3 = (const float*)d_in[8];
  float* out = (float*)d_out;

  const int E = in_sizes[1];
  const int n_nodes = in_sizes[0] / 256;

  const size_t offB1 = 0;
  const size_t offW2 = (size_t)512 * 256 * 2;                 // 262144
  const size_t offPQ = offW2 + (size_t)256 * 256 * 2;         // 393216
  const size_t need = offPQ + (size_t)n_nodes * 512 * 2;      // ~51.6 MB

  if (ws_size >= need) {
    unsigned short* B1  = (unsigned short*)((char*)d_ws + offB1);
    unsigned short* W2b = (unsigned short*)((char*)d_ws + offW2);
    unsigned short* PQ  = (unsigned short*)((char*)d_ws + offPQ);
    k_prep<<<768, 256, 0, stream>>>(W1, W2, B1, W2b);
    const int ntiles_node = (n_nodes + 63) / 64;
    k_node<<<256, 512, 0, stream>>>(x, B1, b1, PQ, n_nodes, ntiles_node);
    const int ntiles = (E + E_TILE - 1) / E_TILE;
    k_edge<<<256, 256, 0, stream>>>(PQ, src, dst, W2b, b2, W3, b3, out, E, ntiles);
  } else {
    k_fallback<<<(E + 3) / 4, 256, 0, stream>>>(x, src, dst, W1, b1, W2, b2, W3, b3, out, E);
  }
}

// Round 20
// 208.249 us; speedup vs baseline: 1.2498x; 1.2498x over previous
//
#include <hip/hip_runtime.h>

typedef short bfx8 __attribute__((ext_vector_type(8)));
typedef float fx4 __attribute__((ext_vector_type(4)));

#define D 256
#define E_TILE 32

__device__ __forceinline__ float b2f(short s) {
  union { unsigned u; float f; } v; v.u = ((unsigned)(unsigned short)s) << 16; return v.f;
}
__device__ __forceinline__ short f2b(float f) {
  union { float f; unsigned u; } v; v.f = f;
  unsigned u = v.u;
  u += 0x7fffu + ((u >> 16) & 1u);   // RNE
  return (short)(u >> 16);
}
__device__ __forceinline__ float relu(float f) { return f > 0.f ? f : 0.f; }

// ---------------- prep: convert weights to bf16 in ws ----------------
__global__ void k_prep(const float* __restrict__ W1, const float* __restrict__ W2,
                       unsigned short* __restrict__ B1, unsigned short* __restrict__ W2b) {
  int t = blockIdx.x * 256 + threadIdx.x;
  if (t < 512 * 256) {
    int n = t >> 8, k = t & 255;
    float v = (n < 256) ? W1[n * 512 + k] : W1[(n - 256) * 512 + 256 + k];
    B1[t] = (unsigned short)f2b(v);
  } else if (t < 512 * 256 + 256 * 256) {
    int i = t - 512 * 256;
    W2b[i] = (unsigned short)f2b(W2[i]);
  }
}

// ---------------- node kernel v2 (unchanged): PQ = x @ B1^T + [b1;0] ------
__launch_bounds__(512, 1)
__global__ void k_node(const float* __restrict__ x, const unsigned short* __restrict__ B1,
                       const float* __restrict__ b1,
                       unsigned short* __restrict__ PQ, int n_nodes, int ntiles) {
  __shared__ __align__(16) short smA[64 * 264];   // 33.8 KB, stride 264 (pad 8)
  short* smT = smA;                               // [32][520] alias for store transpose
  const int tid = threadIdx.x;
  const int wave = tid >> 6, lane = tid & 63;
  const int lr = lane & 15, lg = lane >> 4;

  bfx8 bw[4][8];
  float b1v[4];
#pragma unroll
  for (int nt = 0; nt < 4; ++nt) {
    int n = wave * 64 + nt * 16 + lr;
    b1v[nt] = (n < 256) ? b1[n] : 0.f;
#pragma unroll
    for (int ks = 0; ks < 8; ++ks)
      bw[nt][ks] = *(const bfx8*)(B1 + n * 256 + ks * 32 + lg * 8);
  }

  const int r  = tid >> 3;
  const int c4 = (tid & 7) * 4;
  const int rs = tid >> 4;
  const int cs = (tid & 15) * 8;

  for (int tile = blockIdx.x; tile < ntiles; tile += gridDim.x) {
    const int m0 = tile * 64;
    {
      int m = m0 + r;
      if (m < n_nodes) {
        const float* p = x + (size_t)m * 256 + c4;
#pragma unroll
        for (int j = 0; j < 8; ++j) {
          float4 v = *(const float4*)(p + j * 32);
          short4 o = { f2b(v.x), f2b(v.y), f2b(v.z), f2b(v.w) };
          *(short4*)&smA[r * 264 + c4 + j * 32] = o;
        }
      } else {
        short4 z = {0, 0, 0, 0};
#pragma unroll
        for (int j = 0; j < 8; ++j)
          *(short4*)&smA[r * 264 + c4 + j * 32] = z;
      }
    }
    __syncthreads();

    fx4 acc[4][4] = {};
#pragma unroll
    for (int ks = 0; ks < 8; ++ks) {
      bfx8 af[4];
#pragma unroll
      for (int mt = 0; mt < 4; ++mt)
        af[mt] = *(const bfx8*)&smA[(mt * 16 + lr) * 264 + ks * 32 + lg * 8];
#pragma unroll
      for (int nt = 0; nt < 4; ++nt)
#pragma unroll
        for (int mt = 0; mt < 4; ++mt)
          acc[mt][nt] = __builtin_amdgcn_mfma_f32_16x16x32_bf16(af[mt], bw[nt][ks], acc[mt][nt], 0, 0, 0);
    }
    __syncthreads();

#pragma unroll
    for (int h = 0; h < 2; ++h) {
#pragma unroll
      for (int mt2 = 0; mt2 < 2; ++mt2) {
        const int mt = 2 * h + mt2;
#pragma unroll
        for (int nt = 0; nt < 4; ++nt)
#pragma unroll
          for (int i = 0; i < 4; ++i) {
            int mrow = mt2 * 16 + lg * 4 + i;
            int n = wave * 64 + nt * 16 + lr;
            smT[mrow * 520 + n] = f2b(acc[mt][nt][i] + b1v[nt]);
          }
      }
      __syncthreads();
      int m = m0 + h * 32 + rs;
      if (m < n_nodes) {
#pragma unroll
        for (int j = 0; j < 4; ++j) {
          int c = cs + j * 128;
          *(bfx8*)(PQ + (size_t)m * 512 + c) = *(const bfx8*)&smT[rs * 520 + c];
        }
      }
      __syncthreads();
    }
  }
}

// ---- async stage for k_edge v4: one global_load_lds per edge (32 edges/tile) ----
// lanes 0-31 fetch P'[src[e]] (512B), lanes 32-63 fetch Q[dst[e]] (+512B).
// Wave w stages rows [8w, 8w+8) == exactly the rows wave w's fuse reads.
__device__ __forceinline__ void stage_tile(const unsigned short* __restrict__ PQ,
                                           const int* __restrict__ src,
                                           const int* __restrict__ dst,
                                           short* smRaw, int ebase, int w, int lane, int E) {
  int eidx = ebase + w * 8 + (lane & 7);
  if (eidx > E - 1) eidx = E - 1;             // clamp: tail rows load edge E-1 (finite data, rows unused)
  int vs = src[eidx];
  int vd = dst[eidx];
  const char* pqc = (const char*)PQ;
#pragma unroll
  for (int i = 0; i < 8; ++i) {
    int ss = __builtin_amdgcn_readlane(vs, i);
    int sd = __builtin_amdgcn_readlane(vd, i);
    const char* gp = (lane < 32)
        ? pqc + (size_t)ss * 1024 + (size_t)lane * 16
        : pqc + (size_t)sd * 1024 + 512 + (size_t)(lane - 32) * 16;
    __builtin_amdgcn_global_load_lds((const void*)gp, (void*)&smRaw[(w * 8 + i) * 520], 16, 0, 0);
  }
}

// ---------------- edge kernel v4: async gather, E_TILE=32 to restore 2 blocks/CU -------
// ROUND-14. Round-13 (E_TILE=64 async) measured the decisive fact: gather rate
// is PROPORTIONAL to resident waves (1 block/CU -> 1.05 TB/s, exactly half of
// round-7's 1.9 TB/s at 2 blocks/CU) -> the random gather is MLP x latency
// bound, NOT at a memory-system ceiling. Fix: halve the tile so LDS fits 2
// blocks/CU (raw 33.3KB + smH 16.9KB + smS 0.5KB = 50.7KB; x2 = 101KB <= 160KB)
// while keeping the async next-tile prefetch -> 8 waves/CU AND ~2x outstanding
// gather bytes vs round 7. Regs: bw[4][8]=128 (N64/wave), acc[2][4]=32 (M32),
// af[2]=8 -> peak ~210 < 256, same bucket, no spill expected.
//   per tile: fuse(raw->smH) | (1) | stage(t+G)->raw | GEMM | epi | (2) | out
// Null outcome (dur ~85, rate ~1.9 TB/s) => pattern ceiling; revert to round-7.
__launch_bounds__(256, 2)
__global__ void k_edge(const unsigned short* __restrict__ PQ,
                       const int* __restrict__ src, const int* __restrict__ dst,
                       const unsigned short* __restrict__ W2b,
                       const float* __restrict__ b2, const float* __restrict__ W3,
                       const float* __restrict__ b3, float* __restrict__ out,
                       int E, int ntiles) {
  __shared__ __align__(16) short smRaw[32 * 520];  // [edge][0:256]=P', [256:512]=Q, pad 8
  __shared__ __align__(16) short smH[32 * 264];    // h1, stride 264 (pad 8)
  __shared__ float smS[4][32];
  const int tid = threadIdx.x;
  const int wave = tid >> 6, lane = tid & 63;
  const int lr = lane & 15, lg = lane >> 4;
  const int G = gridDim.x;

  // W2 fragments (this wave's 64 N rows, full K=256): 4 n-tiles x 8 k-steps
  bfx8 bw[4][8];
  float b2v[4], w3v[4];
#pragma unroll
  for (int nt = 0; nt < 4; ++nt) {
    int n = wave * 64 + nt * 16 + lr;
    b2v[nt] = b2[n];
    w3v[nt] = W3[n];
#pragma unroll
    for (int ks = 0; ks < 8; ++ks)
      bw[nt][ks] = *(const bfx8*)(W2b + n * 256 + ks * 32 + lg * 8);
  }
  const float b3v = b3[0];

  const int r = tid >> 3, cb = (tid & 7) * 8;   // fuse role: 8 thr/edge; r in [8w,8w+8) ✓
  const int t0 = blockIdx.x;

  // prologue: stage tile t0, wait for it (vmcnt(0) drained at the barrier)
  if (t0 < ntiles) stage_tile(PQ, src, dst, smRaw, t0 * E_TILE, wave, lane, E);
  __syncthreads();

  for (int t = t0; t < ntiles; t += G) {
    // fuse layer1 from raw LDS: h1 = relu(P'+Q)  (b1 already folded into P')
#pragma unroll
    for (int it = 0; it < 4; ++it) {
      int c = cb + it * 64;
      bfx8 pv = *(const bfx8*)&smRaw[r * 520 + c];
      bfx8 qv = *(const bfx8*)&smRaw[r * 520 + 256 + c];
      bfx8 o;
#pragma unroll
      for (int j = 0; j < 8; ++j)
        o[j] = f2b(relu(b2f(pv[j]) + b2f(qv[j])));
      *(bfx8*)&smH[r * 264 + c] = o;
    }
    __syncthreads();                                   // (1) smH visible; raw consumed

    // issue next tile's gather: flies during GEMM+epilogue, drained at (2)
    if (t + G < ntiles)
      stage_tile(PQ, src, dst, smRaw, (t + G) * E_TILE, wave, lane, E);

    // layer2 GEMM: 32M x 64N per wave, K=256
    fx4 acc[2][4] = {};
#pragma unroll
    for (int ks = 0; ks < 8; ++ks) {
      bfx8 af[2];
#pragma unroll
      for (int mt = 0; mt < 2; ++mt)
        af[mt] = *(const bfx8*)&smH[(mt * 16 + lr) * 264 + ks * 32 + lg * 8];
#pragma unroll
      for (int nt = 0; nt < 4; ++nt)
#pragma unroll
        for (int mt = 0; mt < 2; ++mt)
          acc[mt][nt] = __builtin_amdgcn_mfma_f32_16x16x32_bf16(af[mt], bw[nt][ks], acc[mt][nt], 0, 0, 0);
    }

    // epilogue: relu(acc+b2) dot w3, shfl-reduce within 16-groups
#pragma unroll
    for (int mt = 0; mt < 2; ++mt)
#pragma unroll
      for (int i = 0; i < 4; ++i) {
        float p = 0.f;
#pragma unroll
        for (int nt = 0; nt < 4; ++nt)
          p += relu(acc[mt][nt][i] + b2v[nt]) * w3v[nt];
        p += __shfl_xor(p, 1);
        p += __shfl_xor(p, 2);
        p += __shfl_xor(p, 4);
        p += __shfl_xor(p, 8);
        if (lr == 0) smS[wave][mt * 16 + lg * 4 + i] = p;
      }
    __syncthreads();                                   // (2) smS visible; drains stage loads (post-GEMM)
    if (tid < 32) {
      int e = t * E_TILE + tid;
      if (e < E) out[e] = smS[0][tid] + smS[1][tid] + smS[2][tid] + smS[3][tid] + b3v;
    }
    // loop: fuse(t+G) reads raw (drained at (2)); smS(t+G) written only after next (1)
  }
}

// ---------------- fallback (if ws too small): naive fp32, 1 edge per wave ----------------
__global__ void k_fallback(const float* __restrict__ x, const int* __restrict__ src,
                           const int* __restrict__ dst, const float* __restrict__ W1,
                           const float* __restrict__ b1, const float* __restrict__ W2,
                           const float* __restrict__ b2, const float* __restrict__ W3,
                           const float* __restrict__ b3, float* __restrict__ out, int E) {
  __shared__ float smF[4][512];
  __shared__ float smG[4][256];
  int wave = threadIdx.x >> 6, lane = threadIdx.x & 63;
  int e = blockIdx.x * 4 + wave;
  bool valid = e < E;
  int ec = valid ? e : 0;
  int s = src[ec], d = dst[ec];
  for (int j = 0; j < 8; ++j) {
    int k = lane * 8 + j;
    smF[wave][k] = (k < 256) ? x[(size_t)s * 256 + k] : x[(size_t)d * 256 + k - 256];
  }
  __syncthreads();
  for (int t = 0; t < 4; ++t) {
    int n = lane + t * 64;
    float a = b1[n];
    for (int k = 0; k < 512; ++k) a += smF[wave][k] * W1[n * 512 + k];
    smG[wave][n] = relu(a);
  }
  __syncthreads();
  float p = 0.f;
  for (int t = 0; t < 4; ++t) {
    int n = lane + t * 64;
    float a = b2[n];
    for (int k = 0; k < 256; ++k) a += smG[wave][k] * W2[n * 256 + k];
    p += relu(a) * W3[n];
  }
  for (int m = 1; m < 64; m <<= 1) p += __shfl_xor(p, m);
  if (lane == 0 && valid) out[e] = p + b3[0];
}

extern "C" void kernel_launch(void* const* d_in, const int* in_sizes, int n_in,
                              void* d_out, int out_size, void* d_ws, size_t ws_size,
                              hipStream_t stream) {
  const float* x  = (const float*)d_in[0];
  const int*   src = (const int*)d_in[1];
  const int*   dst = (const int*)d_in[2];
  const float* W1 = (const float*)d_in[3];
  const float* b1 = (const float*)d_in[4];
  const float* W2 = (const float*)d_in[5];
  const float* b2 = (const float*)d_in[6];
  const float* W3 = (const float*)d_in[7];
  const float* b3 = (const float*)d_in[8];
  float* out = (float*)d_out;

  const int E = in_sizes[1];
  const int n_nodes = in_sizes[0] / 256;

  const size_t offB1 = 0;
  const size_t offW2 = (size_t)512 * 256 * 2;                 // 262144
  const size_t offPQ = offW2 + (size_t)256 * 256 * 2;         // 393216
  const size_t need = offPQ + (size_t)n_nodes * 512 * 2;      // ~51.6 MB

  if (ws_size >= need) {
    unsigned short* B1  = (unsigned short*)((char*)d_ws + offB1);
    unsigned short* W2b = (unsigned short*)((char*)d_ws + offW2);
    unsigned short* PQ  = (unsigned short*)((char*)d_ws + offPQ);
    k_prep<<<768, 256, 0, stream>>>(W1, W2, B1, W2b);
    const int ntiles_node = (n_nodes + 63) / 64;
    k_node<<<256, 512, 0, stream>>>(x, B1, b1, PQ, n_nodes, ntiles_node);
    const int ntiles = (E + E_TILE - 1) / E_TILE;
    k_edge<<<512, 256, 0, stream>>>(PQ, src, dst, W2b, b2, W3, b3, out, E, ntiles);
  } else {
    k_fallback<<<(E + 3) / 4, 256, 0, stream>>>(x, src, dst, W1, b1, W2, b2, W3, b3, out, E);
  }
}

// Round 21
// 206.789 us; speedup vs baseline: 1.2586x; 1.0071x over previous
//
#include <hip/hip_runtime.h>

typedef short bfx8 __attribute__((ext_vector_type(8)));
typedef float fx4 __attribute__((ext_vector_type(4)));

#define D 256
#define E_TILE 32

__device__ __forceinline__ float b2f(short s) {
  union { unsigned u; float f; } v; v.u = ((unsigned)(unsigned short)s) << 16; return v.f;
}
__device__ __forceinline__ short f2b(float f) {
  union { float f; unsigned u; } v; v.f = f;
  unsigned u = v.u;
  u += 0x7fffu + ((u >> 16) & 1u);   // RNE
  return (short)(u >> 16);
}
__device__ __forceinline__ float relu(float f) { return f > 0.f ? f : 0.f; }

// ---------------- prep: convert weights to bf16 in ws ----------------
__global__ void k_prep(const float* __restrict__ W1, const float* __restrict__ W2,
                       unsigned short* __restrict__ B1, unsigned short* __restrict__ W2b) {
  int t = blockIdx.x * 256 + threadIdx.x;
  if (t < 512 * 256) {
    int n = t >> 8, k = t & 255;
    float v = (n < 256) ? W1[n * 512 + k] : W1[(n - 256) * 512 + 256 + k];
    B1[t] = (unsigned short)f2b(v);
  } else if (t < 512 * 256 + 256 * 256) {
    int i = t - 512 * 256;
    W2b[i] = (unsigned short)f2b(W2[i]);
  }
}

// ---------------- node kernel v2 (unchanged): PQ = x @ B1^T + [b1;0] ------
__launch_bounds__(512, 1)
__global__ void k_node(const float* __restrict__ x, const unsigned short* __restrict__ B1,
                       const float* __restrict__ b1,
                       unsigned short* __restrict__ PQ, int n_nodes, int ntiles) {
  __shared__ __align__(16) short smA[64 * 264];   // 33.8 KB, stride 264 (pad 8)
  short* smT = smA;                               // [32][520] alias for store transpose
  const int tid = threadIdx.x;
  const int wave = tid >> 6, lane = tid & 63;
  const int lr = lane & 15, lg = lane >> 4;

  bfx8 bw[4][8];
  float b1v[4];
#pragma unroll
  for (int nt = 0; nt < 4; ++nt) {
    int n = wave * 64 + nt * 16 + lr;
    b1v[nt] = (n < 256) ? b1[n] : 0.f;
#pragma unroll
    for (int ks = 0; ks < 8; ++ks)
      bw[nt][ks] = *(const bfx8*)(B1 + n * 256 + ks * 32 + lg * 8);
  }

  const int r  = tid >> 3;
  const int c4 = (tid & 7) * 4;
  const int rs = tid >> 4;
  const int cs = (tid & 15) * 8;

  for (int tile = blockIdx.x; tile < ntiles; tile += gridDim.x) {
    const int m0 = tile * 64;
    {
      int m = m0 + r;
      if (m < n_nodes) {
        const float* p = x + (size_t)m * 256 + c4;
#pragma unroll
        for (int j = 0; j < 8; ++j) {
          float4 v = *(const float4*)(p + j * 32);
          short4 o = { f2b(v.x), f2b(v.y), f2b(v.z), f2b(v.w) };
          *(short4*)&smA[r * 264 + c4 + j * 32] = o;
        }
      } else {
        short4 z = {0, 0, 0, 0};
#pragma unroll
        for (int j = 0; j < 8; ++j)
          *(short4*)&smA[r * 264 + c4 + j * 32] = z;
      }
    }
    __syncthreads();

    fx4 acc[4][4] = {};
#pragma unroll
    for (int ks = 0; ks < 8; ++ks) {
      bfx8 af[4];
#pragma unroll
      for (int mt = 0; mt < 4; ++mt)
        af[mt] = *(const bfx8*)&smA[(mt * 16 + lr) * 264 + ks * 32 + lg * 8];
#pragma unroll
      for (int nt = 0; nt < 4; ++nt)
#pragma unroll
        for (int mt = 0; mt < 4; ++mt)
          acc[mt][nt] = __builtin_amdgcn_mfma_f32_16x16x32_bf16(af[mt], bw[nt][ks], acc[mt][nt], 0, 0, 0);
    }
    __syncthreads();

#pragma unroll
    for (int h = 0; h < 2; ++h) {
#pragma unroll
      for (int mt2 = 0; mt2 < 2; ++mt2) {
        const int mt = 2 * h + mt2;
#pragma unroll
        for (int nt = 0; nt < 4; ++nt)
#pragma unroll
          for (int i = 0; i < 4; ++i) {
            int mrow = mt2 * 16 + lg * 4 + i;
            int n = wave * 64 + nt * 16 + lr;
            smT[mrow * 520 + n] = f2b(acc[mt][nt][i] + b1v[nt]);
          }
      }
      __syncthreads();
      int m = m0 + h * 32 + rs;
      if (m < n_nodes) {
#pragma unroll
        for (int j = 0; j < 4; ++j) {
          int c = cs + j * 128;
          *(bfx8*)(PQ + (size_t)m * 512 + c) = *(const bfx8*)&smT[rs * 520 + c];
        }
      }
      __syncthreads();
    }
  }
}

// ---------------- edge kernel v5: sync reg-gather, 16 waves/CU ----------------
// ROUND-21. Wave-scaling data (r13: 4w->1.05 TB/s; r20: 8w async->1.55; r7: 8w
// sync->1.90) shows gather rate scales with WAVES, async/outstanding-bytes is
// NOT the lever (r20 null), and sync reg-gather beats LDS-direct by ~8%.
// All prior configs were stuck at 8 waves/CU by the 129..256 arch-reg bucket
// (bw[4][8]=128 + acc). v5 halves the per-wave footprint: 512-thr blocks
// (8 waves), each wave owns N=32 -> bw[2][8]=64 VGPRs; E_TILE=32 ->
// acc[2][2]=16 + af[2]=8; peak live ~105 <= 128 -> __launch_bounds__(512,4)
// pins the <=128 bucket -> 4 waves/SIMD -> 2 blocks/CU = 16 waves/CU (2x r7).
// Fuse uses 16 thr/edge -> 256B contiguous segments (vs r7's 64B).
// LDS: smH 16.9KB + smS 1KB = ~18KB -> LDS is nowhere near limiting.
// Watch: WRITE_SIZE jump => forced-cap spill => revert to r7 k_edge.
// Null (Occ 40% but dur ~85): random-gather path ceiling ~2 TB/s independent
// of waves => k_edge at pattern roofline.
__launch_bounds__(512, 4)
__global__ void k_edge(const unsigned short* __restrict__ PQ,
                       const int* __restrict__ src, const int* __restrict__ dst,
                       const unsigned short* __restrict__ W2b,
                       const float* __restrict__ b2, const float* __restrict__ W3,
                       const float* __restrict__ b3, float* __restrict__ out,
                       int E, int ntiles) {
  __shared__ __align__(16) short smH[32 * 264];   // h1, stride 264 (pad 8)
  __shared__ float smS[8][32];
  const int tid = threadIdx.x;
  const int wave = tid >> 6, lane = tid & 63;
  const int lr = lane & 15, lg = lane >> 4;

  // W2 fragments: this wave's 32 N rows, full K=256 -> bw[2][8] = 64 VGPRs
  bfx8 bw[2][8];
  float b2v[2], w3v[2];
#pragma unroll
  for (int nt = 0; nt < 2; ++nt) {
    int n = wave * 32 + nt * 16 + lr;
    b2v[nt] = b2[n];
    w3v[nt] = W3[n];
#pragma unroll
    for (int ks = 0; ks < 8; ++ks)
      bw[nt][ks] = *(const bfx8*)(W2b + n * 256 + ks * 32 + lg * 8);
  }
  const float b3v = b3[0];

  const int r = tid >> 4, cb = (tid & 15) * 8;   // fuse role: 16 thr/edge

  for (int t = blockIdx.x; t < ntiles; t += gridDim.x) {
    const int base = t * E_TILE;
    // gather + fuse layer1: h1 = relu(P'[src]+Q[dst]) -> smH  (b1 folded in P')
    {
      int e = base + r;
      if (e < E) {
        int s = src[e], d = dst[e];
        const unsigned short* ps = PQ + (size_t)s * 512;
        const unsigned short* pd = PQ + (size_t)d * 512 + 256;
#pragma unroll
        for (int it = 0; it < 2; ++it) {
          int c = cb + it * 128;
          bfx8 pv = *(const bfx8*)(ps + c);
          bfx8 qv = *(const bfx8*)(pd + c);
          bfx8 o;
#pragma unroll
          for (int j = 0; j < 8; ++j)
            o[j] = f2b(relu(b2f(pv[j]) + b2f(qv[j])));
          *(bfx8*)&smH[r * 264 + c] = o;
        }
      } else {
        bfx8 z = (bfx8){0,0,0,0,0,0,0,0};
#pragma unroll
        for (int it = 0; it < 2; ++it) {
          int c = cb + it * 128;
          *(bfx8*)&smH[r * 264 + c] = z;
        }
      }
    }
    __syncthreads();

    // layer2 GEMM: 32M x 32N per wave, K=256
    fx4 acc[2][2] = {};
#pragma unroll
    for (int ks = 0; ks < 8; ++ks) {
      bfx8 af[2];
#pragma unroll
      for (int mt = 0; mt < 2; ++mt)
        af[mt] = *(const bfx8*)&smH[(mt * 16 + lr) * 264 + ks * 32 + lg * 8];
#pragma unroll
      for (int nt = 0; nt < 2; ++nt)
#pragma unroll
        for (int mt = 0; mt < 2; ++mt)
          acc[mt][nt] = __builtin_amdgcn_mfma_f32_16x16x32_bf16(af[mt], bw[nt][ks], acc[mt][nt], 0, 0, 0);
    }

    // epilogue: relu(acc+b2) dot w3, shfl-reduce over this wave's 32 n
#pragma unroll
    for (int mt = 0; mt < 2; ++mt)
#pragma unroll
      for (int i = 0; i < 4; ++i) {
        float p = 0.f;
#pragma unroll
        for (int nt = 0; nt < 2; ++nt)
          p += relu(acc[mt][nt][i] + b2v[nt]) * w3v[nt];
        p += __shfl_xor(p, 1);
        p += __shfl_xor(p, 2);
        p += __shfl_xor(p, 4);
        p += __shfl_xor(p, 8);
        if (lr == 0) smS[wave][mt * 16 + lg * 4 + i] = p;
      }
    __syncthreads();
    if (tid < 32) {
      int e = base + tid;
      if (e < E)
        out[e] = smS[0][tid] + smS[1][tid] + smS[2][tid] + smS[3][tid] +
                 smS[4][tid] + smS[5][tid] + smS[6][tid] + smS[7][tid] + b3v;
    }
    // no trailing sync: smS(t+1) writes ordered after out(t) by fuse-sync(t+1)
  }
}

// ---------------- fallback (if ws too small): naive fp32, 1 edge per wave ----------------
__global__ void k_fallback(const float* __restrict__ x, const int* __restrict__ src,
                           const int* __restrict__ dst, const float* __restrict__ W1,
                           const float* __restrict__ b1, const float* __restrict__ W2,
                           const float* __restrict__ b2, const float* __restrict__ W3,
                           const float* __restrict__ b3, float* __restrict__ out, int E) {
  __shared__ float smF[4][512];
  __shared__ float smG[4][256];
  int wave = threadIdx.x >> 6, lane = threadIdx.x & 63;
  int e = blockIdx.x * 4 + wave;
  bool valid = e < E;
  int ec = valid ? e : 0;
  int s = src[ec], d = dst[ec];
  for (int j = 0; j < 8; ++j) {
    int k = lane * 8 + j;
    smF[wave][k] = (k < 256) ? x[(size_t)s * 256 + k] : x[(size_t)d * 256 + k - 256];
  }
  __syncthreads();
  for (int t = 0; t < 4; ++t) {
    int n = lane + t * 64;
    float a = b1[n];
    for (int k = 0; k < 512; ++k) a += smF[wave][k] * W1[n * 512 + k];
    smG[wave][n] = relu(a);
  }
  __syncthreads();
  float p = 0.f;
  for (int t = 0; t < 4; ++t) {
    int n = lane + t * 64;
    float a = b2[n];
    for (int k = 0; k < 256; ++k) a += smG[wave][k] * W2[n * 256 + k];
    p += relu(a) * W3[n];
  }
  for (int m = 1; m < 64; m <<= 1) p += __shfl_xor(p, m);
  if (lane == 0 && valid) out[e] = p + b3[0];
}

extern "C" void kernel_launch(void* const* d_in, const int* in_sizes, int n_in,
                              void* d_out, int out_size, void* d_ws, size_t ws_size,
                              hipStream_t stream) {
  const float* x  = (const float*)d_in[0];
  const int*   src = (const int*)d_in[1];
  const int*   dst = (const int*)d_in[2];
  const float* W1 = (const float*)d_in[3];
  const float* b1 = (const float*)d_in[4];
  const float* W2 = (const float*)d_in[5];
  const float* b2 = (const float*)d_in[6];
  const float* W3 = (const float*)d_in[7];
  const float* b3 = (const float*)d_in[8];
  float* out = (float*)d_out;

  const int E = in_sizes[1];
  const int n_nodes = in_sizes[0] / 256;

  const size_t offB1 = 0;
  const size_t offW2 = (size_t)512 * 256 * 2;                 // 262144
  const size_t offPQ = offW2 + (size_t)256 * 256 * 2;         // 393216
  const size_t need = offPQ + (size_t)n_nodes * 512 * 2;      // ~51.6 MB

  if (ws_size >= need) {
    unsigned short* B1  = (unsigned short*)((char*)d_ws + offB1);
    unsigned short* W2b = (unsigned short*)((char*)d_ws + offW2);
    unsigned short* PQ  = (unsigned short*)((char*)d_ws + offPQ);
    k_prep<<<768, 256, 0, stream>>>(W1, W2, B1, W2b);
    const int ntiles_node = (n_nodes + 63) / 64;
    k_node<<<256, 512, 0, stream>>>(x, B1, b1, PQ, n_nodes, ntiles_node);
    const int ntiles = (E + E_TILE - 1) / E_TILE;
    k_edge<<<512, 512, 0, stream>>>(PQ, src, dst, W2b, b2, W3, b3, out, E, ntiles);
  } else {
    k_fallback<<<(E + 3) / 4, 256, 0, stream>>>(x, src, dst, W1, b1, W2, b2, W3, b3, out, E);
  }
}